// Round 9
// baseline (351.952 us; speedup 1.0000x reference)
//
#include <hip/hip_runtime.h>

#define N_NODES 100000
#define E_EDGES 3200000

// ---- bucket sort geometry ----
#define BSHIFT 7
#define BWIDTH 128                       // src values per bucket
#define NBUCKETS 782                     // ceil(100000/128)
#define NB1 200                          // partition blocks
#define CHUNK1 16000                     // NB1*CHUNK1 == E_EDGES exactly
#define SCAN_LEN (NBUCKETS * NB1)        // 156400
#define SCAN_CHUNK 1024
#define SCAN_BLOCKS 153                  // ceil(156400/1024)

// Wct: transposed fused weight matrix, bf16, [80 cols][264 k-stride]
#define WCT_STRIDE 264
#define WCT_ELEMS (80 * WCT_STRIDE)      // 21120 ushorts

// ---------------------------------------------------------------------------
// ws layout (float slots):
//   hem    [0,        3200000)   N*64 ushort bf16, PERMUTED: hem[d][r*4+n]
//                                 holds h_em[d][16n+r]  (1x dwordx2 gather)
//   s8     [3200000,  4000000)   N*8 f32  [s_src+att_b (4) | s_dst (4)]
//   Wct    [4000000,  4010560)   21120 ushort
//   off8   [4010560,  4010568)   8 f32
//   rowptr [4010568,  4110576)   N+1 ints (+pad)
//   cbase  [4110576,  4266976)   156400 ints
//   bsum   [4266976,  4267232)   256 ints
//   boff   [4267232,  4267488)   256 ints
//   pairs  [4267488,  7467488)   E ints (lsrc<<20 | dst)
//   sdst   [7467488, 10667488)   E ints (dst sorted by src)
//   counts [7467488,  7623888)   OVERLAYS sdst (dead by bsort)
//   ---- fast path only (ws_size >= 69,869,952 B) ----
//   denom  [10667488, 11067488)  N*4 f32 per-node head denominators
//   aw     [11067488, 17467488)  E*4 ushort bf16 edge weights
// fallback footprint 42.67 MB (= proven R8); fast footprint 69.87 MB
// ---------------------------------------------------------------------------

typedef __attribute__((ext_vector_type(8))) short short8;
typedef __attribute__((ext_vector_type(4))) float f32x4;

__device__ __forceinline__ unsigned short f2bf(float f) {
    unsigned u = __float_as_uint(f);
    return (unsigned short)((u + 0x7FFFu + ((u >> 16) & 1u)) >> 16);  // RNE
}

__device__ __forceinline__ float rdlf(float v, int l) {
    return __int_as_float(__builtin_amdgcn_readlane(__float_as_int(v), l));
}

// One wave per k (64 blocks x 4 waves): coalesced loads + shuffle reduce.
__global__ __launch_bounds__(256) void fuse_weights_kernel(
    const float* __restrict__ W_lin, const float* __restrict__ b_lin,
    const float* __restrict__ att_w, const float* __restrict__ emb_w,
    unsigned short* __restrict__ Wct, float* __restrict__ off8) {
    const int wave = threadIdx.x >> 6, lane = threadIdx.x & 63;
    const int k = blockIdx.x * 4 + wave;  // 0..255
    float4 wv = *(const float4*)(W_lin + k * 256 + lane * 4);
    float acc[8];
#pragma unroll
    for (int j = 0; j < 8; ++j) {
        int l = j & 3, part = j >> 2;
        float4 av = *(const float4*)(att_w + l * 512 + part * 256 + lane * 4);
        acc[j] = wv.x * av.x + wv.y * av.y + wv.z * av.z + wv.w * av.w;
    }
#pragma unroll
    for (int j = 0; j < 8; ++j) {
        float v = acc[j];
#pragma unroll
        for (int off = 32; off >= 1; off >>= 1) v += __shfl_xor(v, off);
        acc[j] = v;
    }
    if (lane < 8) {  // static-index select
        float v = acc[0];
#pragma unroll
        for (int j = 1; j < 8; ++j) if (lane == j) v = acc[j];
        Wct[(64 + lane) * WCT_STRIDE + k] = f2bf(v);
    }
    Wct[lane * WCT_STRIDE + k] = f2bf(emb_w[k * 64 + lane]);  // emb transpose
    if (lane < 8) Wct[(72 + lane) * WCT_STRIDE + k] = 0;
    if (k < 8) {  // off8[k] = b_lin . a_row(k)
        int l = k & 3, part = k >> 2;
        float4 av = *(const float4*)(att_w + l * 512 + part * 256 + lane * 4);
        float4 bv = *(const float4*)(b_lin + lane * 4);
        float p = bv.x * av.x + bv.y * av.y + bv.z * av.z + bv.w * av.w;
#pragma unroll
        for (int off = 32; off >= 1; off >>= 1) p += __shfl_xor(p, off);
        if (lane == 0) off8[k] = p;
    }
}

// MFMA row kernel: one wave per 16-row tile, [hem | s8] = X @ Wct^T.
// hem stored PERMUTED: hem[row][r*4+n] = value for original col 16n+r.
__global__ __launch_bounds__(256) void row_mfma_kernel(
    const float* __restrict__ x, const unsigned short* __restrict__ Wct,
    const float* __restrict__ off8, const float* __restrict__ att_b,
    const float* __restrict__ emb_b,
    unsigned short* __restrict__ hem, float* __restrict__ s8) {
    __shared__ unsigned short Wl[WCT_ELEMS];  // stride-264 (2-way, free)
    const int tid = threadIdx.x;
    for (int i = tid; i < WCT_ELEMS / 8; i += 256)
        ((uint4*)Wl)[i] = ((const uint4*)Wct)[i];
    __syncthreads();
    const int wave = tid >> 6, lane = tid & 63;
    const int tile = blockIdx.x * 4 + wave;  // 6250 tiles of 16 rows
    if (tile >= N_NODES / 16) return;
    const int row0 = tile * 16;
    const int r = lane & 15, g = lane >> 4;
    const float* xr = x + (size_t)(row0 + r) * 256 + g * 8;

    f32x4 acc[5];
#pragma unroll
    for (int n = 0; n < 5; ++n) acc[n] = (f32x4){0.f, 0.f, 0.f, 0.f};

    for (int kk = 0; kk < 8; ++kk) {
        float4 xa = *(const float4*)(xr + kk * 32);
        float4 xb = *(const float4*)(xr + kk * 32 + 4);
        short8 a;
        a[0] = (short)f2bf(xa.x); a[1] = (short)f2bf(xa.y);
        a[2] = (short)f2bf(xa.z); a[3] = (short)f2bf(xa.w);
        a[4] = (short)f2bf(xb.x); a[5] = (short)f2bf(xb.y);
        a[6] = (short)f2bf(xb.z); a[7] = (short)f2bf(xb.w);
        const int bk = kk * 32 + g * 8;
#pragma unroll
        for (int n = 0; n < 5; ++n) {
            short8 b = *(const short8*)(&Wl[(16 * n + r) * WCT_STRIDE + bk]);
            acc[n] = __builtin_amdgcn_mfma_f32_16x16x32_bf16(a, b, acc[n], 0, 0, 0);
        }
    }
#pragma unroll
    for (int q = 0; q < 4; ++q) {
        const int orow = row0 + g * 4 + q;
        unsigned e0 = f2bf(acc[0][q] + emb_b[r]);
        unsigned e1 = f2bf(acc[1][q] + emb_b[16 + r]);
        unsigned e2 = f2bf(acc[2][q] + emb_b[32 + r]);
        unsigned e3 = f2bf(acc[3][q] + emb_b[48 + r]);
        uint2 hv;
        hv.x = e0 | (e1 << 16);
        hv.y = e2 | (e3 << 16);
        *(uint2*)(hem + (size_t)orow * 64 + r * 4) = hv;  // permuted row
        if (r < 8)
            s8[(size_t)orow * 8 + r] =
                acc[4][q] + off8[r] + (r < 4 ? att_b[r] : 0.f);
    }
}

// ---- stage 1: per-(block,bucket) counts via LDS histogram ----
__global__ __launch_bounds__(256) void bcount_kernel(const int* __restrict__ src,
                                                     int* __restrict__ counts) {
    __shared__ int h[NBUCKETS];
    for (int i = threadIdx.x; i < NBUCKETS; i += 256) h[i] = 0;
    __syncthreads();
    const int base = blockIdx.x * CHUNK1;
    for (int i = threadIdx.x; i < CHUNK1; i += 256)
        atomicAdd(&h[src[base + i] >> BSHIFT], 1);
    __syncthreads();
    for (int i = threadIdx.x; i < NBUCKETS; i += 256)
        counts[i * NB1 + blockIdx.x] = h[i];
}

// ---- generic 3-kernel exclusive scan over counts[SCAN_LEN] -> cbase ----
__global__ __launch_bounds__(256) void scan1_kernel(const int* __restrict__ counts,
                                                    int* __restrict__ bsum) {
    __shared__ int red[256];
    const int b = blockIdx.x, t = threadIdx.x;
    const int base = b * SCAN_CHUNK;
    int s = 0;
    for (int i = t; i < SCAN_CHUNK; i += 256) {
        int idx = base + i;
        s += (idx < SCAN_LEN) ? counts[idx] : 0;
    }
    red[t] = s;
    __syncthreads();
    for (int off = 128; off >= 1; off >>= 1) {
        if (t < off) red[t] += red[t + off];
        __syncthreads();
    }
    if (t == 0) bsum[b] = red[0];
}

__global__ __launch_bounds__(256) void scan2_kernel(const int* __restrict__ bsum,
                                                    int* __restrict__ boff) {
    __shared__ int sh[256];
    const int t = threadIdx.x;
    sh[t] = (t < SCAN_BLOCKS) ? bsum[t] : 0;
    __syncthreads();
    for (int off = 1; off < 256; off <<= 1) {
        int v = (t >= off) ? sh[t - off] : 0;
        __syncthreads();
        sh[t] += v;
        __syncthreads();
    }
    if (t < SCAN_BLOCKS) boff[t] = (t == 0) ? 0 : sh[t - 1];
}

__global__ __launch_bounds__(256) void scan3_kernel(const int* __restrict__ counts,
                                                    const int* __restrict__ boff,
                                                    int* __restrict__ cbase) {
    __shared__ int sh[256];
    const int b = blockIdx.x, t = threadIdx.x;
    const int base = b * SCAN_CHUNK;
    int running = boff[b];
    for (int tile = 0; tile < SCAN_CHUNK; tile += 256) {
        const int idx = base + tile + t;
        const int v = (idx < SCAN_LEN) ? counts[idx] : 0;
        sh[t] = v;
        __syncthreads();
        for (int off = 1; off < 256; off <<= 1) {
            int u = (t >= off) ? sh[t - off] : 0;
            __syncthreads();
            sh[t] += u;
            __syncthreads();
        }
        if (idx < SCAN_LEN) cbase[idx] = running + sh[t] - v;
        running += sh[255];
        __syncthreads();
    }
}

// ---- stage 2: partition edges into bucket-contiguous regions ----
__global__ __launch_bounds__(256) void bpart_kernel(const int* __restrict__ src,
                                                    const int* __restrict__ dst,
                                                    const int* __restrict__ cbase,
                                                    int* __restrict__ pairs) {
    __shared__ int cur[NBUCKETS];
    for (int i = threadIdx.x; i < NBUCKETS; i += 256)
        cur[i] = cbase[i * NB1 + blockIdx.x];
    __syncthreads();
    const int base = blockIdx.x * CHUNK1;
    for (int i = threadIdx.x; i < CHUNK1; i += 256) {
        int s = src[base + i];
        int pos = atomicAdd(&cur[s >> BSHIFT], 1);
        pairs[pos] = ((s & (BWIDTH - 1)) << 20) | dst[base + i];
    }
}

// ---- stage 3: per-bucket counting sort; emits rowptr + sorted dst.
// FW=1 additionally computes per-edge bf16 weights (aw) and per-node head
// denominators (denom) — s8[src] is L1-hot (128-node window per bucket).
template <int FW>
__global__ __launch_bounds__(256) void bsort_kernel(
    const int* __restrict__ cbase, const int* __restrict__ pairs,
    const float* __restrict__ s8,
    int* __restrict__ sdst, int* __restrict__ rowptr,
    float* __restrict__ denom, unsigned* __restrict__ aw) {
    __shared__ int h[BWIDTH];
    __shared__ float dl[FW ? BWIDTH : 1][4];
    const int b = blockIdx.x, t = threadIdx.x;
    const int beg = cbase[b * NB1];
    const int end = (b == NBUCKETS - 1) ? E_EDGES : cbase[(b + 1) * NB1];
    if (t < BWIDTH) {
        h[t] = 0;
        if constexpr (FW) {
            dl[t][0] = 0.f; dl[t][1] = 0.f; dl[t][2] = 0.f; dl[t][3] = 0.f;
        }
    }
    __syncthreads();
    for (int i = beg + t; i < end; i += 256)
        atomicAdd(&h[pairs[i] >> 20], 1);
    __syncthreads();
    if (t == 0) {  // serial exclusive scan of 128 (cheap)
        int run = 0;
        for (int i = 0; i < BWIDTH; ++i) { int c = h[i]; h[i] = run; run += c; }
    }
    __syncthreads();
    const int s0 = b << BSHIFT;
    if (t < BWIDTH && s0 + t < N_NODES) rowptr[s0 + t] = beg + h[t];
    if (b == NBUCKETS - 1 && t == 0) rowptr[N_NODES] = E_EDGES;
    __syncthreads();  // rowptr reads h before placement mutates it
    for (int i = beg + t; i < end; i += 256) {
        const int p = pairs[i];
        const int lsrc = p >> 20, dst = p & 0xFFFFF;
        const int pos = beg + atomicAdd(&h[lsrc], 1);
        sdst[pos] = dst;
        if constexpr (FW) {
            const float4 ss = *(const float4*)(s8 + (size_t)(s0 + lsrc) * 8);
            const float4 sd = *(const float4*)(s8 + (size_t)dst * 8 + 4);
            const float w0 = __expf(1.f / (1.f + __expf(-(ss.x + sd.x))));
            const float w1 = __expf(1.f / (1.f + __expf(-(ss.y + sd.y))));
            const float w2 = __expf(1.f / (1.f + __expf(-(ss.z + sd.z))));
            const float w3 = __expf(1.f / (1.f + __expf(-(ss.w + sd.w))));
            const unsigned u0 = f2bf(w0), u1 = f2bf(w1);
            const unsigned u2 = f2bf(w2), u3 = f2bf(w3);
            aw[2 * (size_t)pos]     = u0 | (u1 << 16);
            aw[2 * (size_t)pos + 1] = u2 | (u3 << 16);
            // denominator = sum of the SAME bf16-rounded values fed to MFMA
            atomicAdd(&dl[lsrc][0], __uint_as_float(u0 << 16));
            atomicAdd(&dl[lsrc][1], __uint_as_float(u1 << 16));
            atomicAdd(&dl[lsrc][2], __uint_as_float(u2 << 16));
            atomicAdd(&dl[lsrc][3], __uint_as_float(u3 << 16));
        }
    }
    if constexpr (FW) {
        __syncthreads();
        if (t < BWIDTH && s0 + t < N_NODES) {
            float4 dv = make_float4(dl[t][0], dl[t][1], dl[t][2], dl[t][3]);
            *(float4*)(denom + (size_t)(s0 + t) * 4) = dv;
        }
    }
}

// FAST node kernel: weights precomputed (aw), denominators precomputed.
// Per j: sdst load + 2B aw load + one 8B permuted-hem load; chain depth 1.
// A rows 4..15 replicate rows 0..3 (r&3), so all four g-groups hold identical
// accumulators -> epilogue is 4 fully-coalesced 256B stores.
__global__ __launch_bounds__(256) void node_fast_kernel(
    const int* __restrict__ rowptr, const int* __restrict__ sdst,
    const unsigned short* __restrict__ aw, const unsigned short* __restrict__ hem,
    const float* __restrict__ denom, float* __restrict__ out) {
    const int lane = threadIdx.x & 63;
    const int r = lane & 15, g = lane >> 4, r3 = r & 3;
    const int gw = (blockIdx.x * blockDim.x + threadIdx.x) >> 6;
    const int nw = (gridDim.x * blockDim.x) >> 6;
    for (int s = gw; s < N_NODES; s += nw) {
        const int beg = rowptr[s], end = rowptr[s + 1];
        f32x4 acc0 = {0.f, 0.f, 0.f, 0.f}, acc1 = {0.f, 0.f, 0.f, 0.f};
        f32x4 acc2 = {0.f, 0.f, 0.f, 0.f}, acc3 = {0.f, 0.f, 0.f, 0.f};
        for (int base = beg; base < end; base += 32) {
            const int m = end - base;
            short8 a  = {0, 0, 0, 0, 0, 0, 0, 0};
            short8 b0 = {0, 0, 0, 0, 0, 0, 0, 0};
            short8 b1 = {0, 0, 0, 0, 0, 0, 0, 0};
            short8 b2 = {0, 0, 0, 0, 0, 0, 0, 0};
            short8 b3 = {0, 0, 0, 0, 0, 0, 0, 0};
#pragma unroll
            for (int j = 0; j < 8; ++j) {
                if (4 * j < m) {  // wave-uniform -> scalar skip
                    const int e = base + 4 * j + g;
                    const bool valid = (e < end);
                    const int ee = valid ? e : beg;
                    const int dj = sdst[ee];
                    unsigned short wv = aw[(size_t)ee * 4 + r3];
                    a[j] = valid ? (short)wv : (short)0;
                    const uint2 hv = *(const uint2*)(hem + (size_t)dj * 64 + r * 4);
                    b0[j] = (short)(hv.x & 0xFFFFu);
                    b1[j] = (short)(hv.x >> 16);
                    b2[j] = (short)(hv.y & 0xFFFFu);
                    b3[j] = (short)(hv.y >> 16);
                }
            }
            acc0 = __builtin_amdgcn_mfma_f32_16x16x32_bf16(a, b0, acc0, 0, 0, 0);
            acc1 = __builtin_amdgcn_mfma_f32_16x16x32_bf16(a, b1, acc1, 0, 0, 0);
            acc2 = __builtin_amdgcn_mfma_f32_16x16x32_bf16(a, b2, acc2, 0, 0, 0);
            acc3 = __builtin_amdgcn_mfma_f32_16x16x32_bf16(a, b3, acc3, 0, 0, 0);
        }
        const float4 dv = *(const float4*)(denom + (size_t)s * 4);
        const float i0 = dv.x > 0.f ? 1.f / dv.x : 0.f;
        const float i1 = dv.y > 0.f ? 1.f / dv.y : 0.f;
        const float i2 = dv.z > 0.f ? 1.f / dv.z : 0.f;
        const float i3 = dv.w > 0.f ? 1.f / dv.w : 0.f;
        f32x4 av = acc0;                 // g-group selects its column tile
        if (g == 1) av = acc1;
        if (g == 2) av = acc2;
        if (g == 3) av = acc3;
        float* o = out + (size_t)s * 256 + g * 16 + r;
        o[0]   = av[0] * i0;
        o[64]  = av[1] * i1;
        o[128] = av[2] * i2;
        o[192] = av[3] * i3;
    }
}

// FALLBACK node kernel (small ws): R8 fused weights, permuted-hem 8B load.
__global__ __launch_bounds__(256) void node_mfma_kernel(
    const int* __restrict__ rowptr, const int* __restrict__ sdst,
    const float* __restrict__ s8, const unsigned short* __restrict__ hem,
    float* __restrict__ out) {
    const int lane = threadIdx.x & 63;
    const int r = lane & 15, g = lane >> 4;
    const int r3 = r & 3;
    const bool headlane = (r < 4);
    const int gw = (blockIdx.x * blockDim.x + threadIdx.x) >> 6;
    const int nw = (gridDim.x * blockDim.x) >> 6;
    for (int s = gw; s < N_NODES; s += nw) {
        const int beg = rowptr[s], end = rowptr[s + 1];
        const float ssr = s8[(size_t)s * 8 + r3];
        f32x4 acc0 = {0.f, 0.f, 0.f, 0.f}, acc1 = {0.f, 0.f, 0.f, 0.f};
        f32x4 acc2 = {0.f, 0.f, 0.f, 0.f}, acc3 = {0.f, 0.f, 0.f, 0.f};
        float dsum = 0.f;
        for (int base = beg; base < end; base += 32) {
            const int m = end - base;
            short8 a  = {0, 0, 0, 0, 0, 0, 0, 0};
            short8 b0 = {0, 0, 0, 0, 0, 0, 0, 0};
            short8 b1 = {0, 0, 0, 0, 0, 0, 0, 0};
            short8 b2 = {0, 0, 0, 0, 0, 0, 0, 0};
            short8 b3 = {0, 0, 0, 0, 0, 0, 0, 0};
#pragma unroll
            for (int j = 0; j < 8; ++j) {
                if (4 * j < m) {
                    const int e = base + 4 * j + g;
                    const bool valid = (e < end);
                    const int ee = valid ? e : beg;
                    const int dj = sdst[ee];
                    const float sd = s8[(size_t)dj * 8 + 4 + r3];
                    const float t = ssr + sd;
                    const float sg = 1.f / (1.f + __expf(-t));
                    float w = __expf(sg);
                    w = (valid && headlane) ? w : 0.f;
                    const unsigned ub = __float_as_uint(w) & 0xFFFF0000u;
                    a[j] = (short)(ub >> 16);
                    dsum += __uint_as_float(ub);
                    const uint2 hv = *(const uint2*)(hem + (size_t)dj * 64 + r * 4);
                    b0[j] = (short)(hv.x & 0xFFFFu);
                    b1[j] = (short)(hv.x >> 16);
                    b2[j] = (short)(hv.y & 0xFFFFu);
                    b3[j] = (short)(hv.y >> 16);
                }
            }
            acc0 = __builtin_amdgcn_mfma_f32_16x16x32_bf16(a, b0, acc0, 0, 0, 0);
            acc1 = __builtin_amdgcn_mfma_f32_16x16x32_bf16(a, b1, acc1, 0, 0, 0);
            acc2 = __builtin_amdgcn_mfma_f32_16x16x32_bf16(a, b2, acc2, 0, 0, 0);
            acc3 = __builtin_amdgcn_mfma_f32_16x16x32_bf16(a, b3, acc3, 0, 0, 0);
        }
        dsum += __shfl_xor(dsum, 16);
        dsum += __shfl_xor(dsum, 32);
        const float d0 = rdlf(dsum, 0), d1 = rdlf(dsum, 1);
        const float d2 = rdlf(dsum, 2), d3 = rdlf(dsum, 3);
        const float i0 = d0 > 0.f ? 1.f / d0 : 0.f;
        const float i1 = d1 > 0.f ? 1.f / d1 : 0.f;
        const float i2 = d2 > 0.f ? 1.f / d2 : 0.f;
        const float i3 = d3 > 0.f ? 1.f / d3 : 0.f;
        if (g == 0) {
            float* o = out + (size_t)s * 256 + r;
#pragma unroll
            for (int n = 0; n < 4; ++n) {
                o[0 * 64 + n * 16] = acc0[0] * i0, o[1 * 64 + n * 16] = acc0[1] * i1,
                o[2 * 64 + n * 16] = acc0[2] * i2, o[3 * 64 + n * 16] = acc0[3] * i3;
                f32x4 tmp = acc0; acc0 = acc1; acc1 = acc2; acc2 = acc3; acc3 = tmp;
            }
        }
    }
}

extern "C" void kernel_launch(void* const* d_in, const int* in_sizes, int n_in,
                              void* d_out, int out_size, void* d_ws, size_t ws_size,
                              hipStream_t stream) {
    const float* x     = (const float*)d_in[0];
    const int*   src   = (const int*)d_in[1];
    const int*   dst   = (const int*)d_in[2];
    const float* W_lin = (const float*)d_in[3];
    const float* b_lin = (const float*)d_in[4];
    const float* att_w = (const float*)d_in[5];
    const float* att_b = (const float*)d_in[6];
    const float* emb_w = (const float*)d_in[7];
    const float* emb_b = (const float*)d_in[8];
    float* out = (float*)d_out;
    float* ws  = (float*)d_ws;

    unsigned short* hem = (unsigned short*)ws;
    float* s8     = ws + 3200000;
    unsigned short* Wct = (unsigned short*)(ws + 4000000);
    float* off8   = ws + 4010560;
    int*   rowptr = (int*)(ws + 4010568);
    int*   cbase  = (int*)(ws + 4110576);
    int*   bsum   = (int*)(ws + 4266976);
    int*   boff   = (int*)(ws + 4267232);
    int*   pairs  = (int*)(ws + 4267488);
    int*   sdst   = (int*)(ws + 7467488);
    int*   counts = (int*)(ws + 7467488);  // overlays sdst (dead by bsort)
    float* denom  = ws + 10667488;
    unsigned* aw  = (unsigned*)(ws + 11067488);

    const bool fast = ws_size >= (size_t)17467488 * 4;

    fuse_weights_kernel<<<64, 256, 0, stream>>>(W_lin, b_lin, att_w, emb_w,
                                                Wct, off8);
    row_mfma_kernel<<<1563, 256, 0, stream>>>(x, Wct, off8, att_b, emb_b,
                                              hem, s8);
    bcount_kernel<<<NB1, 256, 0, stream>>>(src, counts);
    scan1_kernel<<<SCAN_BLOCKS, 256, 0, stream>>>(counts, bsum);
    scan2_kernel<<<1, 256, 0, stream>>>(bsum, boff);
    scan3_kernel<<<SCAN_BLOCKS, 256, 0, stream>>>(counts, boff, cbase);
    bpart_kernel<<<NB1, 256, 0, stream>>>(src, dst, cbase, pairs);
    if (fast) {
        bsort_kernel<1><<<NBUCKETS, 256, 0, stream>>>(cbase, pairs, s8, sdst,
                                                      rowptr, denom, aw);
        node_fast_kernel<<<4096, 256, 0, stream>>>(
            rowptr, sdst, (const unsigned short*)aw, hem, denom, out);
    } else {
        bsort_kernel<0><<<NBUCKETS, 256, 0, stream>>>(cbase, pairs, s8, sdst,
                                                      rowptr, denom, aw);
        node_mfma_kernel<<<4096, 256, 0, stream>>>(rowptr, sdst, s8, hem, out);
    }
}

// Round 10
// 284.586 us; speedup vs baseline: 1.2367x; 1.2367x over previous
//
#include <hip/hip_runtime.h>

#define N_NODES 100000
#define E_EDGES 3200000

// ---- bucket sort geometry ----
#define BSHIFT 7
#define BWIDTH 128                       // src values per bucket
#define NBUCKETS 782                     // ceil(100000/128)
#define NB1 400                          // partition blocks
#define CHUNK1 8000                      // NB1*CHUNK1 == E_EDGES exactly
#define SCAN_LEN (NBUCKETS * NB1)        // 312800
#define SCAN_CHUNK 1024
#define SCAN_BLOCKS 306                  // ceil(312800/1024)

// Wct: transposed fused weight matrix, bf16, [80 cols][264 k-stride]
#define WCT_STRIDE 264
#define WCT_ELEMS (80 * WCT_STRIDE)      // 21120 ushorts

// ---------------------------------------------------------------------------
// ws layout (float slots):
//   hem    [0,        3200000)   N*64 ushort bf16, PERMUTED: hem[d][r*4+n]
//                                 holds h_em[d][16n+r]  (1x dwordx2 gather)
//   s8     [3200000,  4000000)   N*8 f32  [s_src+att_b (4) | s_dst (4)]
//   Wct    [4000000,  4010560)   21120 ushort
//   off8   [4010560,  4010568)   8 f32
//   rowptr [4010568,  4110576)   N+1 ints (+pad)
//   cbase  [4110576,  4423376)   312800 ints
//   bsum   [4423376,  4423888)   512 ints
//   boff   [4423888,  4424400)   512 ints
//   pairs  [4424400,  7624400)   E ints (lsrc<<20 | dst)
//   sdst   [7624400, 10824400)   E ints (dst sorted by src)
//   counts [7624400,  7937200)   OVERLAYS sdst (dead before bsort writes)
// total 43.3 MB (ws proven >= 69.9 MB in R9's fast path)
// ---------------------------------------------------------------------------

typedef __attribute__((ext_vector_type(8))) short short8;
typedef __attribute__((ext_vector_type(4))) float f32x4;

__device__ __forceinline__ unsigned short f2bf(float f) {
    unsigned u = __float_as_uint(f);
    return (unsigned short)((u + 0x7FFFu + ((u >> 16) & 1u)) >> 16);  // RNE
}

// One wave per k (64 blocks x 4 waves): coalesced loads + shuffle reduce.
__global__ __launch_bounds__(256) void fuse_weights_kernel(
    const float* __restrict__ W_lin, const float* __restrict__ b_lin,
    const float* __restrict__ att_w, const float* __restrict__ emb_w,
    unsigned short* __restrict__ Wct, float* __restrict__ off8) {
    const int wave = threadIdx.x >> 6, lane = threadIdx.x & 63;
    const int k = blockIdx.x * 4 + wave;  // 0..255
    float4 wv = *(const float4*)(W_lin + k * 256 + lane * 4);
    float acc[8];
#pragma unroll
    for (int j = 0; j < 8; ++j) {
        int l = j & 3, part = j >> 2;
        float4 av = *(const float4*)(att_w + l * 512 + part * 256 + lane * 4);
        acc[j] = wv.x * av.x + wv.y * av.y + wv.z * av.z + wv.w * av.w;
    }
#pragma unroll
    for (int j = 0; j < 8; ++j) {
        float v = acc[j];
#pragma unroll
        for (int off = 32; off >= 1; off >>= 1) v += __shfl_xor(v, off);
        acc[j] = v;
    }
    if (lane < 8) {  // static-index select
        float v = acc[0];
#pragma unroll
        for (int j = 1; j < 8; ++j) if (lane == j) v = acc[j];
        Wct[(64 + lane) * WCT_STRIDE + k] = f2bf(v);
    }
    Wct[lane * WCT_STRIDE + k] = f2bf(emb_w[k * 64 + lane]);  // emb transpose
    if (lane < 8) Wct[(72 + lane) * WCT_STRIDE + k] = 0;
    if (k < 8) {  // off8[k] = b_lin . a_row(k)
        int l = k & 3, part = k >> 2;
        float4 av = *(const float4*)(att_w + l * 512 + part * 256 + lane * 4);
        float4 bv = *(const float4*)(b_lin + lane * 4);
        float p = bv.x * av.x + bv.y * av.y + bv.z * av.z + bv.w * av.w;
#pragma unroll
        for (int off = 32; off >= 1; off >>= 1) p += __shfl_xor(p, off);
        if (lane == 0) off8[k] = p;
    }
}

// MFMA row kernel: one wave per 16-row tile, [hem | s8] = X @ Wct^T.
// hem stored PERMUTED: hem[row][r*4+n] = value for original col 16n+r.
__global__ __launch_bounds__(256) void row_mfma_kernel(
    const float* __restrict__ x, const unsigned short* __restrict__ Wct,
    const float* __restrict__ off8, const float* __restrict__ att_b,
    const float* __restrict__ emb_b,
    unsigned short* __restrict__ hem, float* __restrict__ s8) {
    __shared__ unsigned short Wl[WCT_ELEMS];  // stride-264 (2-way, free)
    const int tid = threadIdx.x;
    for (int i = tid; i < WCT_ELEMS / 8; i += 256)
        ((uint4*)Wl)[i] = ((const uint4*)Wct)[i];
    __syncthreads();
    const int wave = tid >> 6, lane = tid & 63;
    const int tile = blockIdx.x * 4 + wave;  // 6250 tiles of 16 rows
    if (tile >= N_NODES / 16) return;
    const int row0 = tile * 16;
    const int r = lane & 15, g = lane >> 4;
    const float* xr = x + (size_t)(row0 + r) * 256 + g * 8;

    f32x4 acc[5];
#pragma unroll
    for (int n = 0; n < 5; ++n) acc[n] = (f32x4){0.f, 0.f, 0.f, 0.f};

    for (int kk = 0; kk < 8; ++kk) {
        float4 xa = *(const float4*)(xr + kk * 32);
        float4 xb = *(const float4*)(xr + kk * 32 + 4);
        short8 a;
        a[0] = (short)f2bf(xa.x); a[1] = (short)f2bf(xa.y);
        a[2] = (short)f2bf(xa.z); a[3] = (short)f2bf(xa.w);
        a[4] = (short)f2bf(xb.x); a[5] = (short)f2bf(xb.y);
        a[6] = (short)f2bf(xb.z); a[7] = (short)f2bf(xb.w);
        const int bk = kk * 32 + g * 8;
#pragma unroll
        for (int n = 0; n < 5; ++n) {
            short8 b = *(const short8*)(&Wl[(16 * n + r) * WCT_STRIDE + bk]);
            acc[n] = __builtin_amdgcn_mfma_f32_16x16x32_bf16(a, b, acc[n], 0, 0, 0);
        }
    }
#pragma unroll
    for (int q = 0; q < 4; ++q) {
        const int orow = row0 + g * 4 + q;
        unsigned e0 = f2bf(acc[0][q] + emb_b[r]);
        unsigned e1 = f2bf(acc[1][q] + emb_b[16 + r]);
        unsigned e2 = f2bf(acc[2][q] + emb_b[32 + r]);
        unsigned e3 = f2bf(acc[3][q] + emb_b[48 + r]);
        uint2 hv;
        hv.x = e0 | (e1 << 16);
        hv.y = e2 | (e3 << 16);
        *(uint2*)(hem + (size_t)orow * 64 + r * 4) = hv;  // permuted row
        if (r < 8)
            s8[(size_t)orow * 8 + r] =
                acc[4][q] + off8[r] + (r < 4 ? att_b[r] : 0.f);
    }
}

// ---- stage 1: per-(block,bucket) counts via LDS histogram ----
__global__ __launch_bounds__(256) void bcount_kernel(const int* __restrict__ src,
                                                     int* __restrict__ counts) {
    __shared__ int h[NBUCKETS];
    for (int i = threadIdx.x; i < NBUCKETS; i += 256) h[i] = 0;
    __syncthreads();
    const int base = blockIdx.x * CHUNK1;
    for (int i = threadIdx.x; i < CHUNK1; i += 256)
        atomicAdd(&h[src[base + i] >> BSHIFT], 1);
    __syncthreads();
    for (int i = threadIdx.x; i < NBUCKETS; i += 256)
        counts[i * NB1 + blockIdx.x] = h[i];
}

// ---- generic 3-kernel exclusive scan over counts[SCAN_LEN] -> cbase ----
__global__ __launch_bounds__(256) void scan1_kernel(const int* __restrict__ counts,
                                                    int* __restrict__ bsum) {
    __shared__ int red[256];
    const int b = blockIdx.x, t = threadIdx.x;
    const int base = b * SCAN_CHUNK;
    int s = 0;
    for (int i = t; i < SCAN_CHUNK; i += 256) {
        int idx = base + i;
        s += (idx < SCAN_LEN) ? counts[idx] : 0;
    }
    red[t] = s;
    __syncthreads();
    for (int off = 128; off >= 1; off >>= 1) {
        if (t < off) red[t] += red[t + off];
        __syncthreads();
    }
    if (t == 0) bsum[b] = red[0];
}

__global__ __launch_bounds__(512) void scan2_kernel(const int* __restrict__ bsum,
                                                    int* __restrict__ boff) {
    __shared__ int sh[512];
    const int t = threadIdx.x;
    sh[t] = (t < SCAN_BLOCKS) ? bsum[t] : 0;
    __syncthreads();
    for (int off = 1; off < 512; off <<= 1) {
        int v = (t >= off) ? sh[t - off] : 0;
        __syncthreads();
        sh[t] += v;
        __syncthreads();
    }
    if (t < SCAN_BLOCKS) boff[t] = (t == 0) ? 0 : sh[t - 1];
}

__global__ __launch_bounds__(256) void scan3_kernel(const int* __restrict__ counts,
                                                    const int* __restrict__ boff,
                                                    int* __restrict__ cbase) {
    __shared__ int sh[256];
    const int b = blockIdx.x, t = threadIdx.x;
    const int base = b * SCAN_CHUNK;
    int running = boff[b];
    for (int tile = 0; tile < SCAN_CHUNK; tile += 256) {
        const int idx = base + tile + t;
        const int v = (idx < SCAN_LEN) ? counts[idx] : 0;
        sh[t] = v;
        __syncthreads();
        for (int off = 1; off < 256; off <<= 1) {
            int u = (t >= off) ? sh[t - off] : 0;
            __syncthreads();
            sh[t] += u;
            __syncthreads();
        }
        if (idx < SCAN_LEN) cbase[idx] = running + sh[t] - v;
        running += sh[255];
        __syncthreads();
    }
}

// ---- stage 2: partition edges into bucket-contiguous regions ----
__global__ __launch_bounds__(256) void bpart_kernel(const int* __restrict__ src,
                                                    const int* __restrict__ dst,
                                                    const int* __restrict__ cbase,
                                                    int* __restrict__ pairs) {
    __shared__ int cur[NBUCKETS];
    for (int i = threadIdx.x; i < NBUCKETS; i += 256)
        cur[i] = cbase[i * NB1 + blockIdx.x];
    __syncthreads();
    const int base = blockIdx.x * CHUNK1;
    for (int i = threadIdx.x; i < CHUNK1; i += 256) {
        int s = src[base + i];
        int pos = atomicAdd(&cur[s >> BSHIFT], 1);
        pairs[pos] = ((s & (BWIDTH - 1)) << 20) | dst[base + i];
    }
}

// ---- stage 3: per-bucket counting sort; emits rowptr + sorted dst ----
__global__ __launch_bounds__(256) void bsort_kernel(const int* __restrict__ cbase,
                                                    const int* __restrict__ pairs,
                                                    int* __restrict__ sdst,
                                                    int* __restrict__ rowptr) {
    __shared__ int h[BWIDTH];
    const int b = blockIdx.x, t = threadIdx.x;
    const int beg = cbase[b * NB1];
    const int end = (b == NBUCKETS - 1) ? E_EDGES : cbase[(b + 1) * NB1];
    if (t < BWIDTH) h[t] = 0;
    __syncthreads();
    for (int i = beg + t; i < end; i += 256)
        atomicAdd(&h[pairs[i] >> 20], 1);
    __syncthreads();
    if (t == 0) {  // serial exclusive scan of 128 (cheap)
        int run = 0;
        for (int i = 0; i < BWIDTH; ++i) { int c = h[i]; h[i] = run; run += c; }
    }
    __syncthreads();
    const int s0 = b << BSHIFT;
    if (t < BWIDTH && s0 + t < N_NODES) rowptr[s0 + t] = beg + h[t];
    if (b == NBUCKETS - 1 && t == 0) rowptr[N_NODES] = E_EDGES;
    __syncthreads();  // rowptr reads h before placement mutates it
    for (int i = beg + t; i < end; i += 256) {
        int p = pairs[i];
        int pos = beg + atomicAdd(&h[p >> 20], 1);
        sdst[pos] = p & 0xFFFFF;
    }
}

// Fused MFMA node kernel. Per j: sdst load + 4B sd load + weight chain (2 exp)
// + one 8B permuted-hem load. Denominator via 5th MFMA against constant-ones B:
// accd[q] = sum_e bf16(w[e,q]) on EVERY lane (A rows replicated, row&3 == q),
// so no cross-lane reduction and no denom storage anywhere.
// A rows replicated across r (head = r&3) -> all four g-groups hold identical
// numerators; epilogue is 4 fully-coalesced 256B stores.
__global__ __launch_bounds__(256) void node_kernel(
    const int* __restrict__ rowptr, const int* __restrict__ sdst,
    const float* __restrict__ s8, const unsigned short* __restrict__ hem,
    float* __restrict__ out) {
    const int lane = threadIdx.x & 63;
    const int r = lane & 15, g = lane >> 4, r3 = r & 3;
    const short8 bones = {16256, 16256, 16256, 16256,
                          16256, 16256, 16256, 16256};  // bf16 1.0 x8
    const int gw = (blockIdx.x * blockDim.x + threadIdx.x) >> 6;
    const int nw = (gridDim.x * blockDim.x) >> 6;
    for (int s = gw; s < N_NODES; s += nw) {
        const int beg = rowptr[s], end = rowptr[s + 1];
        const float ssr = s8[(size_t)s * 8 + r3];  // src half, +att_b folded
        f32x4 acc0 = {0.f, 0.f, 0.f, 0.f}, acc1 = {0.f, 0.f, 0.f, 0.f};
        f32x4 acc2 = {0.f, 0.f, 0.f, 0.f}, acc3 = {0.f, 0.f, 0.f, 0.f};
        f32x4 accd = {0.f, 0.f, 0.f, 0.f};
        for (int base = beg; base < end; base += 32) {
            const int m = end - base;
            short8 a  = {0, 0, 0, 0, 0, 0, 0, 0};
            short8 b0 = {0, 0, 0, 0, 0, 0, 0, 0};
            short8 b1 = {0, 0, 0, 0, 0, 0, 0, 0};
            short8 b2 = {0, 0, 0, 0, 0, 0, 0, 0};
            short8 b3 = {0, 0, 0, 0, 0, 0, 0, 0};
#pragma unroll
            for (int j = 0; j < 8; ++j) {
                if (4 * j < m) {  // wave-uniform -> scalar skip
                    const int e = base + 4 * j + g;
                    const bool valid = (e < end);
                    const int ee = valid ? e : beg;
                    const int dj = sdst[ee];
                    const float sd = s8[(size_t)dj * 8 + 4 + r3];
                    const float t = ssr + sd;
                    const float sg = 1.f / (1.f + __expf(-t));
                    float w = __expf(sg);
                    w = valid ? w : 0.f;
                    const unsigned ub = __float_as_uint(w) & 0xFFFF0000u;
                    a[j] = (short)(ub >> 16);  // truncated bf16 (num==den)
                    const uint2 hv = *(const uint2*)(hem + (size_t)dj * 64 + r * 4);
                    b0[j] = (short)(hv.x & 0xFFFFu);
                    b1[j] = (short)(hv.x >> 16);
                    b2[j] = (short)(hv.y & 0xFFFFu);
                    b3[j] = (short)(hv.y >> 16);
                }
            }
            acc0 = __builtin_amdgcn_mfma_f32_16x16x32_bf16(a, b0, acc0, 0, 0, 0);
            acc1 = __builtin_amdgcn_mfma_f32_16x16x32_bf16(a, b1, acc1, 0, 0, 0);
            acc2 = __builtin_amdgcn_mfma_f32_16x16x32_bf16(a, b2, acc2, 0, 0, 0);
            acc3 = __builtin_amdgcn_mfma_f32_16x16x32_bf16(a, b3, acc3, 0, 0, 0);
            accd = __builtin_amdgcn_mfma_f32_16x16x32_bf16(a, bones, accd, 0, 0, 0);
        }
        const float i0 = accd[0] > 0.f ? 1.f / accd[0] : 0.f;
        const float i1 = accd[1] > 0.f ? 1.f / accd[1] : 0.f;
        const float i2 = accd[2] > 0.f ? 1.f / accd[2] : 0.f;
        const float i3 = accd[3] > 0.f ? 1.f / accd[3] : 0.f;
        f32x4 av = acc0;                 // g-group selects its column tile
        if (g == 1) av = acc1;
        if (g == 2) av = acc2;
        if (g == 3) av = acc3;
        float* o = out + (size_t)s * 256 + g * 16 + r;
        o[0]   = av[0] * i0;
        o[64]  = av[1] * i1;
        o[128] = av[2] * i2;
        o[192] = av[3] * i3;
    }
}

extern "C" void kernel_launch(void* const* d_in, const int* in_sizes, int n_in,
                              void* d_out, int out_size, void* d_ws, size_t ws_size,
                              hipStream_t stream) {
    const float* x     = (const float*)d_in[0];
    const int*   src   = (const int*)d_in[1];
    const int*   dst   = (const int*)d_in[2];
    const float* W_lin = (const float*)d_in[3];
    const float* b_lin = (const float*)d_in[4];
    const float* att_w = (const float*)d_in[5];
    const float* att_b = (const float*)d_in[6];
    const float* emb_w = (const float*)d_in[7];
    const float* emb_b = (const float*)d_in[8];
    float* out = (float*)d_out;
    float* ws  = (float*)d_ws;

    unsigned short* hem = (unsigned short*)ws;
    float* s8     = ws + 3200000;
    unsigned short* Wct = (unsigned short*)(ws + 4000000);
    float* off8   = ws + 4010560;
    int*   rowptr = (int*)(ws + 4010568);
    int*   cbase  = (int*)(ws + 4110576);
    int*   bsum   = (int*)(ws + 4423376);
    int*   boff   = (int*)(ws + 4423888);
    int*   pairs  = (int*)(ws + 4424400);
    int*   sdst   = (int*)(ws + 7624400);
    int*   counts = (int*)(ws + 7624400);  // overlays sdst (dead by bsort)

    fuse_weights_kernel<<<64, 256, 0, stream>>>(W_lin, b_lin, att_w, emb_w,
                                                Wct, off8);
    row_mfma_kernel<<<1563, 256, 0, stream>>>(x, Wct, off8, att_b, emb_b,
                                              hem, s8);
    bcount_kernel<<<NB1, 256, 0, stream>>>(src, counts);
    scan1_kernel<<<SCAN_BLOCKS, 256, 0, stream>>>(counts, bsum);
    scan2_kernel<<<1, 512, 0, stream>>>(bsum, boff);
    scan3_kernel<<<SCAN_BLOCKS, 256, 0, stream>>>(counts, boff, cbase);
    bpart_kernel<<<NB1, 256, 0, stream>>>(src, dst, cbase, pairs);
    bsort_kernel<<<NBUCKETS, 256, 0, stream>>>(cbase, pairs, sdst, rowptr);
    node_kernel<<<4096, 256, 0, stream>>>(rowptr, sdst, s8, hem, out);
}

// Round 11
// 258.954 us; speedup vs baseline: 1.3591x; 1.0990x over previous
//
#include <hip/hip_runtime.h>

#define N_NODES 100000
#define E_EDGES 3200000

// ---- bucket sort geometry ----
#define BSHIFT 7
#define BWIDTH 128                       // src values per bucket
#define NBUCKETS 782                     // ceil(100000/128)
#define NB1 400                          // partition blocks
#define CHUNK1 8000                      // NB1*CHUNK1 == E_EDGES exactly
#define SCAN_LEN (NBUCKETS * NB1)        // 312800
#define SCAN_CHUNK 1024
#define SCAN_BLOCKS 306                  // ceil(312800/1024)

// Wct: transposed fused weight matrix, bf16, [80 cols][264 k-stride]
#define WCT_STRIDE 264
#define WCT_ELEMS (80 * WCT_STRIDE)      // 21120 ushorts

#define N_TILES (N_NODES / 16)           // 6250

// ---------------------------------------------------------------------------
// ws layout (float slots):
//   hem    [0,        3200000)   N*64 ushort bf16, PERMUTED: hem[d][r*4+n]
//                                 holds h_em[d][16n+r]  (1x dwordx2 gather)
//   s8     [3200000,  4000000)   N*8 f32  [s_src+att_b (4) | s_dst (4)]
//   Wct    [4000000,  4010560)   21120 ushort
//   off8   [4010560,  4010568)   8 f32
//   rowptr [4010568,  4110576)   N+1 ints (+pad)
//   cbase  [4110576,  4423376)   312800 ints
//   bsum   [4423376,  4423888)   512 ints
//   boff   [4423888,  4424400)   512 ints
//   pairs  [4424400,  7624400)   E ints (lsrc<<20 | dst)
//   sdst   [7624400, 10824400)   E ints (dst sorted by src)
//   counts [7624400,  7937200)   OVERLAYS sdst (dead before bsort writes)
// total 43.3 MB
// ---------------------------------------------------------------------------

typedef __attribute__((ext_vector_type(8))) short short8;
typedef __attribute__((ext_vector_type(4))) float f32x4;

__device__ __forceinline__ unsigned short f2bf(float f) {
    unsigned u = __float_as_uint(f);
    return (unsigned short)((u + 0x7FFFu + ((u >> 16) & 1u)) >> 16);  // RNE
}

// One wave per k (64 blocks x 4 waves): coalesced loads + shuffle reduce.
__global__ __launch_bounds__(256) void fuse_weights_kernel(
    const float* __restrict__ W_lin, const float* __restrict__ b_lin,
    const float* __restrict__ att_w, const float* __restrict__ emb_w,
    unsigned short* __restrict__ Wct, float* __restrict__ off8) {
    const int wave = threadIdx.x >> 6, lane = threadIdx.x & 63;
    const int k = blockIdx.x * 4 + wave;  // 0..255
    float4 wv = *(const float4*)(W_lin + k * 256 + lane * 4);
    float acc[8];
#pragma unroll
    for (int j = 0; j < 8; ++j) {
        int l = j & 3, part = j >> 2;
        float4 av = *(const float4*)(att_w + l * 512 + part * 256 + lane * 4);
        acc[j] = wv.x * av.x + wv.y * av.y + wv.z * av.z + wv.w * av.w;
    }
#pragma unroll
    for (int j = 0; j < 8; ++j) {
        float v = acc[j];
#pragma unroll
        for (int off = 32; off >= 1; off >>= 1) v += __shfl_xor(v, off);
        acc[j] = v;
    }
    if (lane < 8) {  // static-index select
        float v = acc[0];
#pragma unroll
        for (int j = 1; j < 8; ++j) if (lane == j) v = acc[j];
        Wct[(64 + lane) * WCT_STRIDE + k] = f2bf(v);
    }
    Wct[lane * WCT_STRIDE + k] = f2bf(emb_w[k * 64 + lane]);  // emb transpose
    if (lane < 8) Wct[(72 + lane) * WCT_STRIDE + k] = 0;
    if (k < 8) {  // off8[k] = b_lin . a_row(k)
        int l = k & 3, part = k >> 2;
        float4 av = *(const float4*)(att_w + l * 512 + part * 256 + lane * 4);
        float4 bv = *(const float4*)(b_lin + lane * 4);
        float p = bv.x * av.x + bv.y * av.y + bv.z * av.z + bv.w * av.w;
#pragma unroll
        for (int off = 32; off >= 1; off >>= 1) p += __shfl_xor(p, off);
        if (lane == 0) off8[k] = p;
    }
}

// MFMA row kernel: persistent-ish blocks (768 = 3/CU), wave-strided tiles so
// the 42KB Wl staging amortizes over ~8 tiles/block instead of 4.
// hem stored PERMUTED: hem[row][r*4+n] = value for original col 16n+r.
__global__ __launch_bounds__(256) void row_mfma_kernel(
    const float* __restrict__ x, const unsigned short* __restrict__ Wct,
    const float* __restrict__ off8, const float* __restrict__ att_b,
    const float* __restrict__ emb_b,
    unsigned short* __restrict__ hem, float* __restrict__ s8) {
    __shared__ unsigned short Wl[WCT_ELEMS];  // stride-264 (2-way, free)
    const int tid = threadIdx.x;
    for (int i = tid; i < WCT_ELEMS / 8; i += 256)
        ((uint4*)Wl)[i] = ((const uint4*)Wct)[i];
    __syncthreads();
    const int wave = tid >> 6, lane = tid & 63;
    const int r = lane & 15, g = lane >> 4;
    const int gw = blockIdx.x * 4 + wave, nw = gridDim.x * 4;
    for (int tile = gw; tile < N_TILES; tile += nw) {
        const int row0 = tile * 16;
        const float* xr = x + (size_t)(row0 + r) * 256 + g * 8;

        f32x4 acc[5];
#pragma unroll
        for (int n = 0; n < 5; ++n) acc[n] = (f32x4){0.f, 0.f, 0.f, 0.f};

        for (int kk = 0; kk < 8; ++kk) {
            float4 xa = *(const float4*)(xr + kk * 32);
            float4 xb = *(const float4*)(xr + kk * 32 + 4);
            short8 a;
            a[0] = (short)f2bf(xa.x); a[1] = (short)f2bf(xa.y);
            a[2] = (short)f2bf(xa.z); a[3] = (short)f2bf(xa.w);
            a[4] = (short)f2bf(xb.x); a[5] = (short)f2bf(xb.y);
            a[6] = (short)f2bf(xb.z); a[7] = (short)f2bf(xb.w);
            const int bk = kk * 32 + g * 8;
#pragma unroll
            for (int n = 0; n < 5; ++n) {
                short8 b = *(const short8*)(&Wl[(16 * n + r) * WCT_STRIDE + bk]);
                acc[n] = __builtin_amdgcn_mfma_f32_16x16x32_bf16(a, b, acc[n],
                                                                 0, 0, 0);
            }
        }
#pragma unroll
        for (int q = 0; q < 4; ++q) {
            const int orow = row0 + g * 4 + q;
            unsigned e0 = f2bf(acc[0][q] + emb_b[r]);
            unsigned e1 = f2bf(acc[1][q] + emb_b[16 + r]);
            unsigned e2 = f2bf(acc[2][q] + emb_b[32 + r]);
            unsigned e3 = f2bf(acc[3][q] + emb_b[48 + r]);
            uint2 hv;
            hv.x = e0 | (e1 << 16);
            hv.y = e2 | (e3 << 16);
            *(uint2*)(hem + (size_t)orow * 64 + r * 4) = hv;  // permuted row
            if (r < 8)
                s8[(size_t)orow * 8 + r] =
                    acc[4][q] + off8[r] + (r < 4 ? att_b[r] : 0.f);
        }
    }
}

// ---- stage 1: per-(block,bucket) counts via LDS histogram ----
__global__ __launch_bounds__(256) void bcount_kernel(const int* __restrict__ src,
                                                     int* __restrict__ counts) {
    __shared__ int h[NBUCKETS];
    for (int i = threadIdx.x; i < NBUCKETS; i += 256) h[i] = 0;
    __syncthreads();
    const int base = blockIdx.x * CHUNK1;
    for (int i = threadIdx.x; i < CHUNK1; i += 256)
        atomicAdd(&h[src[base + i] >> BSHIFT], 1);
    __syncthreads();
    for (int i = threadIdx.x; i < NBUCKETS; i += 256)
        counts[i * NB1 + blockIdx.x] = h[i];
}

// ---- generic 3-kernel exclusive scan over counts[SCAN_LEN] -> cbase ----
__global__ __launch_bounds__(256) void scan1_kernel(const int* __restrict__ counts,
                                                    int* __restrict__ bsum) {
    __shared__ int red[256];
    const int b = blockIdx.x, t = threadIdx.x;
    const int base = b * SCAN_CHUNK;
    int s = 0;
    for (int i = t; i < SCAN_CHUNK; i += 256) {
        int idx = base + i;
        s += (idx < SCAN_LEN) ? counts[idx] : 0;
    }
    red[t] = s;
    __syncthreads();
    for (int off = 128; off >= 1; off >>= 1) {
        if (t < off) red[t] += red[t + off];
        __syncthreads();
    }
    if (t == 0) bsum[b] = red[0];
}

__global__ __launch_bounds__(512) void scan2_kernel(const int* __restrict__ bsum,
                                                    int* __restrict__ boff) {
    __shared__ int sh[512];
    const int t = threadIdx.x;
    sh[t] = (t < SCAN_BLOCKS) ? bsum[t] : 0;
    __syncthreads();
    for (int off = 1; off < 512; off <<= 1) {
        int v = (t >= off) ? sh[t - off] : 0;
        __syncthreads();
        sh[t] += v;
        __syncthreads();
    }
    if (t < SCAN_BLOCKS) boff[t] = (t == 0) ? 0 : sh[t - 1];
}

__global__ __launch_bounds__(256) void scan3_kernel(const int* __restrict__ counts,
                                                    const int* __restrict__ boff,
                                                    int* __restrict__ cbase) {
    __shared__ int sh[256];
    const int b = blockIdx.x, t = threadIdx.x;
    const int base = b * SCAN_CHUNK;
    int running = boff[b];
    for (int tile = 0; tile < SCAN_CHUNK; tile += 256) {
        const int idx = base + tile + t;
        const int v = (idx < SCAN_LEN) ? counts[idx] : 0;
        sh[t] = v;
        __syncthreads();
        for (int off = 1; off < 256; off <<= 1) {
            int u = (t >= off) ? sh[t - off] : 0;
            __syncthreads();
            sh[t] += u;
            __syncthreads();
        }
        if (idx < SCAN_LEN) cbase[idx] = running + sh[t] - v;
        running += sh[255];
        __syncthreads();
    }
}

// ---- stage 2: partition edges into bucket-contiguous regions ----
__global__ __launch_bounds__(256) void bpart_kernel(const int* __restrict__ src,
                                                    const int* __restrict__ dst,
                                                    const int* __restrict__ cbase,
                                                    int* __restrict__ pairs) {
    __shared__ int cur[NBUCKETS];
    for (int i = threadIdx.x; i < NBUCKETS; i += 256)
        cur[i] = cbase[i * NB1 + blockIdx.x];
    __syncthreads();
    const int base = blockIdx.x * CHUNK1;
    for (int i = threadIdx.x; i < CHUNK1; i += 256) {
        int s = src[base + i];
        int pos = atomicAdd(&cur[s >> BSHIFT], 1);
        pairs[pos] = ((s & (BWIDTH - 1)) << 20) | dst[base + i];
    }
}

// ---- stage 3: per-bucket counting sort; emits rowptr + sorted dst ----
__global__ __launch_bounds__(256) void bsort_kernel(const int* __restrict__ cbase,
                                                    const int* __restrict__ pairs,
                                                    int* __restrict__ sdst,
                                                    int* __restrict__ rowptr) {
    __shared__ int h[BWIDTH];
    const int b = blockIdx.x, t = threadIdx.x;
    const int beg = cbase[b * NB1];
    const int end = (b == NBUCKETS - 1) ? E_EDGES : cbase[(b + 1) * NB1];
    if (t < BWIDTH) h[t] = 0;
    __syncthreads();
    for (int i = beg + t; i < end; i += 256)
        atomicAdd(&h[pairs[i] >> 20], 1);
    __syncthreads();
    if (t == 0) {  // serial exclusive scan of 128 (cheap)
        int run = 0;
        for (int i = 0; i < BWIDTH; ++i) { int c = h[i]; h[i] = run; run += c; }
    }
    __syncthreads();
    const int s0 = b << BSHIFT;
    if (t < BWIDTH && s0 + t < N_NODES) rowptr[s0 + t] = beg + h[t];
    if (b == NBUCKETS - 1 && t == 0) rowptr[N_NODES] = E_EDGES;
    __syncthreads();  // rowptr reads h before placement mutates it
    for (int i = beg + t; i < end; i += 256) {
        int p = pairs[i];
        int pos = beg + atomicAdd(&h[p >> 20], 1);
        sdst[pos] = p & 0xFFFFF;
    }
}

// Per-batch body: 3 unrolled passes (8 sdst loads | 16 dependent gathers |
// chains + frag pack) for deep MLP, then 5 MFMAs. All offsets unsigned
// 32-bit so loads use the saddr+voffset form (no 64-bit address math).
// MASKED=0: full batch of 32 edges, zero validity logic.
template <int MASKED>
__device__ __forceinline__ void node_batch(
    const int* __restrict__ sdst, const float* __restrict__ s8,
    const unsigned short* __restrict__ hem,
    int base, int m, int g, unsigned ru4, int r3, float ssr,
    const short8& bones,
    f32x4& acc0, f32x4& acc1, f32x4& acc2, f32x4& acc3, f32x4& accd) {
    unsigned dj[8];
#pragma unroll
    for (int j = 0; j < 8; ++j) {
        int e = 4 * j + g;
        if (MASKED) e = min(e, m - 1);
        dj[j] = (unsigned)sdst[(unsigned)(base + e)];
    }
    float sd[8];
    uint2 hv[8];
#pragma unroll
    for (int j = 0; j < 8; ++j) {
        sd[j] = s8[dj[j] * 8u + 4u + (unsigned)r3];
        hv[j] = *(const uint2*)(hem + dj[j] * 64u + ru4);
    }
    short8 a, b0, b1, b2, b3;
#pragma unroll
    for (int j = 0; j < 8; ++j) {
        const float t = ssr + sd[j];
        const float sg = 1.f / (1.f + __expf(-t));
        float w = __expf(sg);
        if (MASKED) w = (4 * j + g < m) ? w : 0.f;
        a[j] = (short)(__float_as_uint(w) >> 16);  // truncated bf16
        b0[j] = (short)(hv[j].x & 0xFFFFu);
        b1[j] = (short)(hv[j].x >> 16);
        b2[j] = (short)(hv[j].y & 0xFFFFu);
        b3[j] = (short)(hv[j].y >> 16);
    }
    acc0 = __builtin_amdgcn_mfma_f32_16x16x32_bf16(a, b0, acc0, 0, 0, 0);
    acc1 = __builtin_amdgcn_mfma_f32_16x16x32_bf16(a, b1, acc1, 0, 0, 0);
    acc2 = __builtin_amdgcn_mfma_f32_16x16x32_bf16(a, b2, acc2, 0, 0, 0);
    acc3 = __builtin_amdgcn_mfma_f32_16x16x32_bf16(a, b3, acc3, 0, 0, 0);
    accd = __builtin_amdgcn_mfma_f32_16x16x32_bf16(a, bones, accd, 0, 0, 0);
}

// Fused MFMA node kernel. Denominator via 5th MFMA against constant-ones B:
// accd[q] = sum_e bf16(w[e,q]) on EVERY lane. A rows replicated (head = r&3)
// -> all four g-groups hold identical numerators; epilogue is 4 coalesced
// 256B stores.
__global__ __launch_bounds__(256) void node_kernel(
    const int* __restrict__ rowptr, const int* __restrict__ sdst,
    const float* __restrict__ s8, const unsigned short* __restrict__ hem,
    float* __restrict__ out) {
    const int lane = threadIdx.x & 63;
    const int r = lane & 15, g = lane >> 4, r3 = r & 3;
    const unsigned ru4 = (unsigned)(r * 4);
    const short8 bones = {16256, 16256, 16256, 16256,
                          16256, 16256, 16256, 16256};  // bf16 1.0 x8
    const int gw = (blockIdx.x * blockDim.x + threadIdx.x) >> 6;
    const int nw = (gridDim.x * blockDim.x) >> 6;
    for (int s = gw; s < N_NODES; s += nw) {
        const int beg = rowptr[s], end = rowptr[s + 1];
        const float ssr = s8[(unsigned)s * 8u + (unsigned)r3];  // +att_b
        f32x4 acc0 = {0.f, 0.f, 0.f, 0.f}, acc1 = {0.f, 0.f, 0.f, 0.f};
        f32x4 acc2 = {0.f, 0.f, 0.f, 0.f}, acc3 = {0.f, 0.f, 0.f, 0.f};
        f32x4 accd = {0.f, 0.f, 0.f, 0.f};
        const int nfull = (end - beg) >> 5;
        int base = beg;
        for (int f = 0; f < nfull; ++f, base += 32)
            node_batch<0>(sdst, s8, hem, base, 32, g, ru4, r3, ssr, bones,
                          acc0, acc1, acc2, acc3, accd);
        const int m = end - base;
        if (m > 0)
            node_batch<1>(sdst, s8, hem, base, m, g, ru4, r3, ssr, bones,
                          acc0, acc1, acc2, acc3, accd);
        const float i0 = accd[0] > 0.f ? 1.f / accd[0] : 0.f;
        const float i1 = accd[1] > 0.f ? 1.f / accd[1] : 0.f;
        const float i2 = accd[2] > 0.f ? 1.f / accd[2] : 0.f;
        const float i3 = accd[3] > 0.f ? 1.f / accd[3] : 0.f;
        f32x4 av = acc0;                 // g-group selects its column tile
        if (g == 1) av = acc1;
        if (g == 2) av = acc2;
        if (g == 3) av = acc3;
        float* o = out + (size_t)s * 256 + g * 16 + r;
        o[0]   = av[0] * i0;
        o[64]  = av[1] * i1;
        o[128] = av[2] * i2;
        o[192] = av[3] * i3;
    }
}

extern "C" void kernel_launch(void* const* d_in, const int* in_sizes, int n_in,
                              void* d_out, int out_size, void* d_ws, size_t ws_size,
                              hipStream_t stream) {
    const float* x     = (const float*)d_in[0];
    const int*   src   = (const int*)d_in[1];
    const int*   dst   = (const int*)d_in[2];
    const float* W_lin = (const float*)d_in[3];
    const float* b_lin = (const float*)d_in[4];
    const float* att_w = (const float*)d_in[5];
    const float* att_b = (const float*)d_in[6];
    const float* emb_w = (const float*)d_in[7];
    const float* emb_b = (const float*)d_in[8];
    float* out = (float*)d_out;
    float* ws  = (float*)d_ws;

    unsigned short* hem = (unsigned short*)ws;
    float* s8     = ws + 3200000;
    unsigned short* Wct = (unsigned short*)(ws + 4000000);
    float* off8   = ws + 4010560;
    int*   rowptr = (int*)(ws + 4010568);
    int*   cbase  = (int*)(ws + 4110576);
    int*   bsum   = (int*)(ws + 4423376);
    int*   boff   = (int*)(ws + 4423888);
    int*   pairs  = (int*)(ws + 4424400);
    int*   sdst   = (int*)(ws + 7624400);
    int*   counts = (int*)(ws + 7624400);  // overlays sdst (dead by bsort)

    fuse_weights_kernel<<<64, 256, 0, stream>>>(W_lin, b_lin, att_w, emb_w,
                                                Wct, off8);
    row_mfma_kernel<<<768, 256, 0, stream>>>(x, Wct, off8, att_b, emb_b,
                                             hem, s8);
    bcount_kernel<<<NB1, 256, 0, stream>>>(src, counts);
    scan1_kernel<<<SCAN_BLOCKS, 256, 0, stream>>>(counts, bsum);
    scan2_kernel<<<1, 512, 0, stream>>>(bsum, boff);
    scan3_kernel<<<SCAN_BLOCKS, 256, 0, stream>>>(counts, boff, cbase);
    bpart_kernel<<<NB1, 256, 0, stream>>>(src, dst, cbase, pairs);
    bsort_kernel<<<NBUCKETS, 256, 0, stream>>>(cbase, pairs, sdst, rowptr);
    node_kernel<<<4096, 256, 0, stream>>>(rowptr, sdst, s8, hem, out);
}